// Round 8
// baseline (614.875 us; speedup 1.0000x reference)
//
#include <hip/hip_runtime.h>
#include <hip/hip_bf16.h>

// MoE block: H=2048, F=8192, E=8, top-2, T=512 tokens. All inputs fp32.
// Round 8: depth-2 B-prefetch (triple-buffered LDS, one counted vmcnt per
// iter) + A fragments loaded DIRECTLY global->VGPR (r1-verified fragment
// map; A is L2-resident). No A-LDS, no ds_write: single sync point per
// iteration. B staging map byte-identical to rounds 3/4/7 (proven).

#define HDIM 2048
#define FDIM 8192
#define NEXP 8
#define NTOK 512
#define MAXT 512

typedef __attribute__((ext_vector_type(8))) short short8;
typedef __attribute__((ext_vector_type(4))) float f32x4;
typedef unsigned int u32;
typedef unsigned short u16;

__device__ __forceinline__ unsigned cvtpk(float lo, float hi) {
    unsigned r;
    asm("v_cvt_pk_bf16_f32 %0, %1, %2" : "=v"(r) : "v"(lo), "v"(hi));
    return r;
}
__device__ __forceinline__ unsigned f2bf1(float f) {
    unsigned u = __builtin_bit_cast(unsigned, f);
    return (u + 0x7FFFu + ((u >> 16) & 1u)) >> 16;
}
__device__ __forceinline__ void gload16(const void* g, void* l) {
    __builtin_amdgcn_global_load_lds((const __attribute__((address_space(1))) u32*)g,
                                     (__attribute__((address_space(3))) u32*)l, 16, 0, 0);
}
#define SBAR() __builtin_amdgcn_sched_barrier(0)

// ---------------------------------------------------------------- router
__global__ void moe_router(const float* __restrict__ x, const float* __restrict__ Wg,
                           int* __restrict__ counts, int* __restrict__ tok_id,
                           float* __restrict__ tok_w) {
    const int t = blockIdx.x;
    const int lane = threadIdx.x;
    const float* xr = x + (size_t)t * HDIM;
    float acc[8];
    #pragma unroll
    for (int e = 0; e < 8; ++e) acc[e] = 0.f;
    #pragma unroll 4
    for (int i = 0; i < HDIM / 64; ++i) {
        int h = lane + i * 64;
        float xv = xr[h];
        const float4* wr = (const float4*)(Wg + (size_t)h * 8);
        float4 wa = wr[0], wb = wr[1];
        acc[0] += xv * wa.x; acc[1] += xv * wa.y; acc[2] += xv * wa.z; acc[3] += xv * wa.w;
        acc[4] += xv * wb.x; acc[5] += xv * wb.y; acc[6] += xv * wb.z; acc[7] += xv * wb.w;
    }
    #pragma unroll
    for (int off = 32; off >= 1; off >>= 1) {
        #pragma unroll
        for (int e = 0; e < 8; ++e) acc[e] += __shfl_xor(acc[e], off);
    }
    if (lane == 0) {
        int e0 = 0;
        #pragma unroll
        for (int e = 1; e < 8; ++e) if (acc[e] > acc[e0]) e0 = e;
        int e1 = (e0 == 0) ? 1 : 0;
        #pragma unroll
        for (int e = 0; e < 8; ++e) if (e != e0 && acc[e] > acc[e1]) e1 = e;
        float w0 = 1.f / (1.f + __expf(acc[e1] - acc[e0]));
        float w1 = 1.f - w0;
        int s0 = atomicAdd(&counts[e0], 1);
        tok_id[e0 * MAXT + s0] = t; tok_w[e0 * MAXT + s0] = w0;
        int s1 = atomicAdd(&counts[e1], 1);
        tok_id[e1 * MAXT + s1] = t; tok_w[e1 * MAXT + s1] = w1;
    }
}

__global__ void moe_scan(const int* __restrict__ counts, int* __restrict__ offsets) {
    if (threadIdx.x == 0) {
        int a = 0;
        for (int e = 0; e < NEXP; ++e) { offsets[e] = a; a += counts[e]; }
    }
}

// ------------------------------------------------------------- x -> bf16
__global__ void moe_xcvt(const float* __restrict__ x, u16* __restrict__ xbf) {
    const int i = (blockIdx.x * 256 + threadIdx.x) * 8;
    float4 a = *(const float4*)(x + i);
    float4 b = *(const float4*)(x + i + 4);
    uint4 q;
    q.x = cvtpk(a.x, a.y); q.y = cvtpk(a.z, a.w);
    q.z = cvtpk(b.x, b.y); q.w = cvtpk(b.z, b.w);
    *(uint4*)(xbf + i) = q;
}

// B-fragment build: weights fp32 in LDS as [32 k][64 n], dword slot
// n' = n ^ (((k>>3)&1)<<4). 8x ds_read_b32 (2-way = free) + 4 cvt_pk.
__device__ __forceinline__ short8 bfrag(const float* sB, int kbase, int nsw) {
    const float* p = sB + kbase * 64 + nsw;
    float f[8];
    #pragma unroll
    for (int j = 0; j < 8; ++j) f[j] = p[j * 64];
    uint4 q;
    q.x = cvtpk(f[0], f[1]); q.y = cvtpk(f[2], f[3]);
    q.z = cvtpk(f[4], f[5]); q.w = cvtpk(f[6], f[7]);
    return __builtin_bit_cast(short8, q);
}

// ---------------------------------------------------------------- GEMM1
// h[slot,n] = relu(x W1) * (x W3), bf16 out. BM=128 BN=64 BK=32, waves 2x2.
// B depth-2 (3 buffers), A direct-to-reg depth-1. One vmcnt wait per iter.
__global__ __launch_bounds__(256, 2)
void moe_gemm1(const u16* __restrict__ xbf, const float* __restrict__ W1,
               const float* __restrict__ W3, const int* __restrict__ counts,
               const int* __restrict__ offsets, const int* __restrict__ tok_id,
               u16* __restrict__ hbuf) {
    const int nt = blockIdx.x, mt = blockIdx.y, e = blockIdx.z;
    const int cnt = counts[e];
    if (mt * 128 >= cnt) return;
    const int n0 = nt * 64;
    const int tid = threadIdx.x;
    const int w = tid >> 6, l = tid & 63;

    __shared__ __align__(16) float sB1[3 * 2048];
    __shared__ __align__(16) float sB3[3 * 2048];

    const int wr = (w >> 1) * 64, wc = (w & 1) * 32;
    const int lr = l & 15, lg = l >> 4;
    const int lk = lg * 8;
    const int g1 = lg & 1;

    // A fragment base pointers: lane covers row wr+mi*16+lr, k-chunk lg*8.
    const u16* abase[4];
    #pragma unroll
    for (int mi = 0; mi < 4; ++mi) {
        int slot = mt * 128 + wr + mi * 16 + lr;
        int tok = tok_id[e * MAXT + (slot < cnt ? slot : cnt - 1)];
        abase[mi] = xbf + (size_t)tok * HDIM + lk;
    }
    // B staging map (proven r3/r4/r7): instr i covers krow = i*16 + w*4 +
    // (l>>4), chunk c4 = l&15; source chunk pre-XOR'd by k-octet bit.
    const int kr = l >> 4, c4 = l & 15;
    const size_t wstride = (size_t)HDIM * FDIM;
    const float* b1p[2]; const float* b3p[2];
    #pragma unroll
    for (int i = 0; i < 2; ++i) {
        int krow = i * 16 + w * 4 + kr;
        size_t off = (size_t)e * wstride + (size_t)krow * FDIM + n0 +
                     (size_t)((c4 ^ (((krow >> 3) & 1) << 2)) * 4);
        b1p[i] = W1 + off; b3p[i] = W3 + off;
    }

    f32x4 acc1[4][2], acc3[4][2];
    #pragma unroll
    for (int mi = 0; mi < 4; ++mi)
        #pragma unroll
        for (int ni = 0; ni < 2; ++ni) { acc1[mi][ni] = (f32x4)0.f; acc3[mi][ni] = (f32x4)0.f; }

    uint4 afA[4], afB[4];
    unsigned o0 = 0, o1 = 2048, o2 = 4096;

    #define AISSUE1(AF, kt)                                                    \
        _Pragma("unroll")                                                      \
        for (int mi = 0; mi < 4; ++mi)                                         \
            AF[mi] = *(const uint4*)(abase[mi] + (size_t)(kt) * 32);
    #define BSTAGE1(ob, kt)                                                    \
        _Pragma("unroll")                                                      \
        for (int i = 0; i < 2; ++i) {                                          \
            gload16(b1p[i] + (size_t)(kt) * 32 * FDIM, &sB1[(ob) + (i * 16 + w * 4) * 64]); \
            gload16(b3p[i] + (size_t)(kt) * 32 * FDIM, &sB3[(ob) + (i * 16 + w * 4) * 64]); \
        }
    #define MFMAP1(AF, ob)                                                     \
        _Pragma("unroll")                                                      \
        for (int ni = 0; ni < 2; ++ni) {                                       \
            const int nsw = (wc + ni * 16 + lr) ^ (g1 << 4);                   \
            short8 b1 = bfrag(sB1 + (ob), lk, nsw);                            \
            short8 b3 = bfrag(sB3 + (ob), lk, nsw);                            \
            _Pragma("unroll")                                                  \
            for (int mi = 0; mi < 4; ++mi) {                                   \
                short8 a_ = __builtin_bit_cast(short8, AF[mi]);                \
                acc1[mi][ni] = __builtin_amdgcn_mfma_f32_16x16x32_bf16(a_, b1, acc1[mi][ni], 0, 0, 0); \
                acc3[mi][ni] = __builtin_amdgcn_mfma_f32_16x16x32_bf16(a_, b3, acc3[mi][ni], 0, 0, 0); \
            }                                                                  \
        }
    // Body: issue A(kt+1), B(kt+2); wait retires exactly B(kt)+A(kt).
    #define BODY1(kt, oCur, oStg, ARD, ALD, VM)                                \
        SBAR(); AISSUE1(ALD, (kt) + 1); SBAR();                                \
        BSTAGE1(oStg, (kt) + 2); SBAR();                                       \
        asm volatile("s_waitcnt vmcnt(" VM ")" ::: "memory"); SBAR();          \
        __builtin_amdgcn_s_barrier(); SBAR();                                  \
        MFMAP1(ARD, oCur); SBAR();                                             \
        __builtin_amdgcn_s_barrier();

    // Prologue: queue = [B0(4), A0(4), B1(4)] = 12.
    BSTAGE1(o0, 0); SBAR();
    AISSUE1(afA, 0); SBAR();
    BSTAGE1(o1, 1);
    // Main: kt = 0..61 (all issues valid). Steady wait vmcnt(12).
    for (int kt = 0; kt < 62; kt += 2) {
        BODY1(kt, o0, o2, afA, afB, "12");
        BODY1(kt + 1, o1, o0, afB, afA, "12");
        unsigned t_ = o0; o0 = o2; o2 = o1; o1 = t_;   // (o0,o1,o2) <- (o2,o0,o1)
    }
    // Tail kt=62: issue A(63) only; queue [B62,A62,B63,A63]=16 -> vmcnt(8).
    SBAR(); AISSUE1(afB, 63); SBAR();
    asm volatile("s_waitcnt vmcnt(8)" ::: "memory"); SBAR();
    __builtin_amdgcn_s_barrier(); SBAR();
    MFMAP1(afA, o0); SBAR();
    __builtin_amdgcn_s_barrier(); SBAR();
    // Tail kt=63: queue [B63,A63]=8 -> vmcnt(0).
    asm volatile("s_waitcnt vmcnt(0)" ::: "memory"); SBAR();
    __builtin_amdgcn_s_barrier(); SBAR();
    MFMAP1(afB, o1); SBAR();

    #undef AISSUE1
    #undef BSTAGE1
    #undef MFMAP1
    #undef BODY1

    // ---- epilogue: h = relu(h1)*h3 -> bf16 compact rows
    const int hbase = offsets[e] + mt * 128;
    #pragma unroll
    for (int mi = 0; mi < 4; ++mi)
        #pragma unroll
        for (int ni = 0; ni < 2; ++ni)
            #pragma unroll
            for (int r = 0; r < 4; ++r) {
                int rl = wr + mi * 16 + (l >> 4) * 4 + r;
                int sl = mt * 128 + rl;
                if (sl < cnt) {
                    float v1 = acc1[mi][ni][r];
                    v1 = v1 > 0.f ? v1 : 0.f;
                    float hv = v1 * acc3[mi][ni][r];
                    hbuf[(size_t)(hbase + rl) * FDIM + (n0 + wc + ni * 16 + lr)] =
                        (u16)f2bf1(hv);
                }
            }
}

// ---------------------------------------------------------------- GEMM2
// out[t,n] += w * (h W2). BM=128 BN=64 BK=32, split-K x4. B depth-2,
// A direct-to-reg. One vmcnt wait per iter.
__global__ __launch_bounds__(256, 2)
void moe_gemm2(const u16* __restrict__ hbuf, const float* __restrict__ W2,
               const int* __restrict__ counts, const int* __restrict__ offsets,
               const int* __restrict__ tok_id, const float* __restrict__ tok_w,
               float* __restrict__ out) {
    const int nt = blockIdx.x, e = blockIdx.z;
    const int mt = blockIdx.y & 3, ksp = blockIdx.y >> 2;
    const int cnt = counts[e];
    if (mt * 128 >= cnt) return;
    const int n0 = nt * 64;
    const int tid = threadIdx.x;
    const int w = tid >> 6, l = tid & 63;

    __shared__ __align__(16) float sB[3 * 2048];

    const int wr = (w >> 1) * 64, wc = (w & 1) * 32;
    const int lr = l & 15, lg = l >> 4;
    const int lk = lg * 8;
    const int g1 = lg & 1;

    // A fragment bases from hbuf (bf16, compact rows; tail rows stale ->
    // garbage acc rows, masked in epilogue; rows bounded by mt guard).
    const u16* abase[4];
    #pragma unroll
    for (int mi = 0; mi < 4; ++mi) {
        int hrow = offsets[e] + mt * 128 + wr + mi * 16 + lr;
        abase[mi] = hbuf + (size_t)hrow * FDIM + ksp * 2048 + lk;
    }
    const int kr = l >> 4, c4 = l & 15;
    const float* b2p[2];
    #pragma unroll
    for (int i = 0; i < 2; ++i) {
        int krow = i * 16 + w * 4 + kr;
        b2p[i] = W2 + (size_t)e * ((size_t)FDIM * HDIM) + (size_t)(ksp * 2048 + krow) * HDIM +
                 n0 + (size_t)((c4 ^ (((krow >> 3) & 1) << 2)) * 4);
    }

    f32x4 acc[4][2];
    #pragma unroll
    for (int mi = 0; mi < 4; ++mi)
        #pragma unroll
        for (int ni = 0; ni < 2; ++ni) acc[mi][ni] = (f32x4)0.f;

    uint4 afA[4], afB[4];
    unsigned o0 = 0, o1 = 2048, o2 = 4096;

    #define AISSUE2(AF, kt)                                                    \
        _Pragma("unroll")                                                      \
        for (int mi = 0; mi < 4; ++mi)                                         \
            AF[mi] = *(const uint4*)(abase[mi] + (size_t)(kt) * 32);
    #define BSTAGE2(ob, kt)                                                    \
        _Pragma("unroll")                                                      \
        for (int i = 0; i < 2; ++i)                                            \
            gload16(b2p[i] + (size_t)(kt) * 32 * HDIM, &sB[(ob) + (i * 16 + w * 4) * 64]);
    #define MFMAP2(AF, ob)                                                     \
        _Pragma("unroll")                                                      \
        for (int ni = 0; ni < 2; ++ni) {                                       \
            const int nsw = (wc + ni * 16 + lr) ^ (g1 << 4);                   \
            short8 b = bfrag(sB + (ob), lk, nsw);                              \
            _Pragma("unroll")                                                  \
            for (int mi = 0; mi < 4; ++mi) {                                   \
                short8 a_ = __builtin_bit_cast(short8, AF[mi]);                \
                acc[mi][ni] = __builtin_amdgcn_mfma_f32_16x16x32_bf16(a_, b, acc[mi][ni], 0, 0, 0); \
            }                                                                  \
        }
    #define BODY2(kt, oCur, oStg, ARD, ALD, VM)                                \
        SBAR(); AISSUE2(ALD, (kt) + 1); SBAR();                                \
        BSTAGE2(oStg, (kt) + 2); SBAR();                                       \
        asm volatile("s_waitcnt vmcnt(" VM ")" ::: "memory"); SBAR();          \
        __builtin_amdgcn_s_barrier(); SBAR();                                  \
        MFMAP2(ARD, oCur); SBAR();                                             \
        __builtin_amdgcn_s_barrier();

    // Prologue: queue = [B0(2), A0(4), B1(2)] = 8. Steady wait vmcnt(8).
    BSTAGE2(o0, 0); SBAR();
    AISSUE2(afA, 0); SBAR();
    BSTAGE2(o1, 1);
    for (int kt = 0; kt < 62; kt += 2) {
        BODY2(kt, o0, o2, afA, afB, "8");
        BODY2(kt + 1, o1, o0, afB, afA, "8");
        unsigned t_ = o0; o0 = o2; o2 = o1; o1 = t_;
    }
    // Tail kt=62: queue [B62(2),A62(4),B63(2),A63(4)]=12 -> vmcnt(6).
    SBAR(); AISSUE2(afB, 63); SBAR();
    asm volatile("s_waitcnt vmcnt(6)" ::: "memory"); SBAR();
    __builtin_amdgcn_s_barrier(); SBAR();
    MFMAP2(afA, o0); SBAR();
    __builtin_amdgcn_s_barrier(); SBAR();
    // Tail kt=63: queue [B63(2),A63(4)]=6 -> vmcnt(0).
    asm volatile("s_waitcnt vmcnt(0)" ::: "memory"); SBAR();
    __builtin_amdgcn_s_barrier(); SBAR();
    MFMAP2(afB, o1); SBAR();

    #undef AISSUE2
    #undef BSTAGE2
    #undef MFMAP2
    #undef BODY2

    // ---- epilogue: scaled partial scatter-add
    #pragma unroll
    for (int mi = 0; mi < 4; ++mi)
        #pragma unroll
        for (int ni = 0; ni < 2; ++ni)
            #pragma unroll
            for (int r = 0; r < 4; ++r) {
                int rl = wr + mi * 16 + (l >> 4) * 4 + r;
                int sl = mt * 128 + rl;
                if (sl < cnt) {
                    int tk = tok_id[e * MAXT + sl];
                    float wgt = tok_w[e * MAXT + sl];
                    atomicAdd(&out[(size_t)tk * HDIM + (n0 + wc + ni * 16 + lr)],
                              wgt * acc[mi][ni][r]);
                }
            }
}

// ---------------------------------------------------------------- launch
extern "C" void kernel_launch(void* const* d_in, const int* in_sizes, int n_in,
                              void* d_out, int out_size, void* d_ws, size_t ws_size,
                              hipStream_t stream) {
    const float* x  = (const float*)d_in[0];
    const float* Wg = (const float*)d_in[1];
    const float* W1 = (const float*)d_in[2];
    const float* W2 = (const float*)d_in[3];
    const float* W3 = (const float*)d_in[4];
    float* out = (float*)d_out;

    char* ws = (char*)d_ws;
    int*   counts  = (int*)(ws + 0);
    int*   offsets = (int*)(ws + 32);
    int*   tok_id  = (int*)(ws + 64);
    float* tok_w   = (float*)(ws + 64 + NEXP * MAXT * 4);
    u16*   xbf     = (u16*)(ws + 65536);                            // 512x2048 bf16 = 2MB
    u16*   hbuf    = (u16*)(ws + 65536 + (size_t)NTOK * HDIM * 2);  // (1024+128)x8192 bf16

    hipMemsetAsync(ws, 0, 64, stream);
    hipMemsetAsync(d_out, 0, (size_t)out_size * sizeof(float), stream);

    moe_router<<<NTOK, 64, 0, stream>>>(x, Wg, counts, tok_id, tok_w);
    moe_scan<<<1, 64, 0, stream>>>(counts, offsets);
    moe_xcvt<<<NTOK * HDIM / (256 * 8), 256, 0, stream>>>(x, xbf);
    moe_gemm1<<<dim3(FDIM / 64, 4, NEXP), 256, 0, stream>>>(xbf, W1, W3, counts, offsets, tok_id, hbuf);
    moe_gemm2<<<dim3(HDIM / 64, 16, NEXP), 256, 0, stream>>>(hbuf, W2, counts, offsets, tok_id, tok_w, out);
}